// Round 16
// baseline (126.805 us; speedup 1.0000x reference)
//
#include <hip/hip_runtime.h>
#include <hip/hip_bf16.h>

#define BB   2048
#define TT   240
#define DD   90
#define MM   (BB*TT)          // 491520
#define KDIM (TT*DD)          // 21600
#define NCLS 40
#define NPAD 48               // k2 N padded to 3 MFMA col-tiles
#define KS2  45               // k2 split-K chunks
#define KST  15               // k-steps (x32) per chunk: 45*15*32 = 21600

typedef __bf16 bf16x8 __attribute__((ext_vector_type(8)));
typedef float  f32x4  __attribute__((ext_vector_type(4)));

#define LOG2E  1.44269504f
#define LOG2E2 2.88539008f

__device__ __forceinline__ bf16x8 cvt8(float4 a, float4 b){
    bf16x8 r;
    r[0]=(__bf16)a.x; r[1]=(__bf16)a.y; r[2]=(__bf16)a.z; r[3]=(__bf16)a.w;
    r[4]=(__bf16)b.x; r[5]=(__bf16)b.y; r[6]=(__bf16)b.z; r[7]=(__bf16)b.w;
    return r;
}

__device__ __forceinline__ unsigned pack_bf16(float a, float b){
    unsigned u0 = (unsigned)__builtin_bit_cast(unsigned short, (__bf16)a);
    unsigned u1 = (unsigned)__builtin_bit_cast(unsigned short, (__bf16)b);
    return u0 | (u1 << 16);
}

// ---------------------------------------------------------------------------
// pack1 (r14/r15-verified): Wtb[c][k] bf16, c = g*96+dd (gates i,g,o),
// k padded 90->104. Rows PRE-SCALED by exp2 constants (i,o: -log2e;
// g: 2*log2e). k=90: bias-hi, k=91: bias-lo (scaled); x-frag supplies 1.0.
// ---------------------------------------------------------------------------
__global__ void pack1(const float* __restrict__ Wih,
                      const float* __restrict__ bih,
                      const float* __restrict__ bhh,
                      __bf16* __restrict__ wtb)
{
    int id = blockIdx.x*256 + threadIdx.x;
    if (id >= 288*13) return;
    int c  = id / 13;
    int k8 = id - c*13;
    int g  = c / 96, dd = c - g*96;
    int row = (g==0 ? dd : (g==1 ? 180+dd : 270+dd));
    float scale = (g==1) ? LOG2E2 : -LOG2E;
    float bv = 0.f, bhi = 0.f, blo = 0.f;
    if (dd < 90){
        bv  = scale * (bih[row] + bhh[row]);
        bhi = (float)(__bf16)bv;
        blo = bv - bhi;
    }
    bf16x8 v;
    #pragma unroll
    for (int e = 0; e < 8; ++e){
        int k = k8*8 + e;
        float f = 0.f;
        if (dd < 90){
            if (k < 90)       f = scale * Wih[row*90 + k];
            else if (k == 90) f = bhi;
            else if (k == 91) f = blo;
        }
        v[e] = (__bf16)f;
    }
    *(bf16x8*)(wtb + c*104 + k8*8) = v;
}

// ---------------------------------------------------------------------------
// pack2: W_out -> bf16, hi only (r15-verified: absmax unchanged). [48][21600].
// ---------------------------------------------------------------------------
__global__ void pack2(const float* __restrict__ W2, __bf16* __restrict__ w2b)
{
    int id = blockIdx.x*256 + threadIdx.x;
    if (id >= NPAD*2700) return;
    int n  = id / 2700;
    int k8 = id - n*2700;
    bf16x8 v;
    if (n < NCLS){
        #pragma unroll
        for (int e = 0; e < 8; ++e)
            v[e] = (__bf16)W2[(size_t)n*KDIM + k8*8 + e];
    } else {
        #pragma unroll
        for (int e = 0; e < 8; ++e) v[e] = (__bf16)0.f;
    }
    *(bf16x8*)(w2b + (size_t)n*KDIM + k8*8) = v;
}

// ---------------------------------------------------------------------------
// init_logits: seed logits[2048][48] with b_out (pads 0). Runs every call
// (self-cleaning: harness does not re-poison between replays).
// ---------------------------------------------------------------------------
__global__ void init_logits(const float* __restrict__ bout,
                            float* __restrict__ logits)
{
    int g = blockIdx.x*256 + threadIdx.x;
    if (g >= BB*NPAD) return;
    int n = g % NPAD;
    logits[g] = (n < NCLS) ? bout[n] : 0.f;
}

// ---------------------------------------------------------------------------
// k1: FROZEN (r14/r15-verified 103-us config): W in LDS stride 104,
// launch_bounds(512,2) -> VGPR 96 no spill, single-buffer prefetch,
// C^T MFMA orientation, direct-exp2 epilogue on pre-scaled accumulators.
// ---------------------------------------------------------------------------
__global__ __launch_bounds__(512, 2)
void k1_gates(const float* __restrict__ x,
              const __bf16* __restrict__ wtb,
              __bf16* __restrict__ h)
{
    __shared__ __align__(16) __bf16 wt[288*104];   // 59904 B

    const int tid  = threadIdx.x;
    const int lane = tid & 63;
    const int wv   = tid >> 6;      // 0..7
    const int rg   = wv >> 1;       // row group 0..3
    const int nh   = wv & 1;        // N half 0..1
    const int l15  = lane & 15;
    const int kg   = lane >> 4;     // 0..3

    {
        const float4* src = (const float4*)wtb;
        float4* dst = (float4*)wt;
        #pragma unroll
        for (int i = 0; i < 8; ++i){
            int idx = tid + i*512;
            if (idx < 3744) dst[idx] = src[idx];
        }
    }
    __syncthreads();

    const int tbase = blockIdx.x * 15;     // 512 blocks * 15 tiles * 64 rows

    float4 xr[6];
    float2 xe;
    {
        const float* p = x + ((size_t)tbase*64 + rg*16 + l15)*90;
        #pragma unroll
        for (int ks = 0; ks < 2; ++ks){
            xr[ks*2+0] = *(const float4*)(p + ks*32 + kg*8);
            xr[ks*2+1] = *(const float4*)(p + ks*32 + kg*8 + 4);
        }
        if (kg < 3){
            xr[4] = *(const float4*)(p + 64 + kg*8);
            xr[5] = *(const float4*)(p + 64 + kg*8 + 4);
        } else {
            xe = *(const float2*)(p + 88);
        }
    }

    for (int t = 0; t < 15; ++t){
        bf16x8 af[3];
        af[0] = cvt8(xr[0], xr[1]);
        af[1] = cvt8(xr[2], xr[3]);
        if (kg < 3){
            af[2] = cvt8(xr[4], xr[5]);
        } else {
            bf16x8 z;
            #pragma unroll
            for (int e = 0; e < 8; ++e) z[e] = (__bf16)0.f;
            z[0] = (__bf16)xe.x; z[1] = (__bf16)xe.y;
            z[2] = (__bf16)1.0f; z[3] = (__bf16)1.0f;
            af[2] = z;
        }

        f32x4 acc[3][3];
        #pragma unroll
        for (int g = 0; g < 3; ++g)
            #pragma unroll
            for (int j = 0; j < 3; ++j) acc[g][j] = f32x4{0.f,0.f,0.f,0.f};

        const __bf16* wbase = wt + (nh*48 + l15)*104 + 8*kg;
        #pragma unroll
        for (int g = 0; g < 3; ++g){
            #pragma unroll
            for (int j = 0; j < 3; ++j){
                const __bf16* wrow = wbase + (g*96 + j*16)*104;
                #pragma unroll
                for (int ks = 0; ks < 3; ++ks){
                    bf16x8 wv8 = *(const bf16x8*)(wrow + ks*32);
                    acc[g][j] = __builtin_amdgcn_mfma_f32_16x16x32_bf16(wv8, af[ks], acc[g][j], 0,0,0);
                }
            }
        }

        if (t < 14){
            const float* p = x + ((size_t)(tbase+t+1)*64 + rg*16 + l15)*90;
            #pragma unroll
            for (int ks = 0; ks < 2; ++ks){
                xr[ks*2+0] = *(const float4*)(p + ks*32 + kg*8);
                xr[ks*2+1] = *(const float4*)(p + ks*32 + kg*8 + 4);
            }
            if (kg < 3){
                xr[4] = *(const float4*)(p + 64 + kg*8);
                xr[5] = *(const float4*)(p + 64 + kg*8 + 4);
            } else {
                xe = *(const float2*)(p + 88);
            }
        }

        const size_t mrow = (size_t)(tbase+t)*64 + rg*16 + l15;
        __bf16* hp = h + mrow*90;
        #pragma unroll
        for (int j = 0; j < 3; ++j){
            int dd0 = nh*48 + j*16 + kg*4;
            float hv[4];
            #pragma unroll
            for (int r = 0; r < 4; ++r){
                float ea = exp2f(acc[0][j][r]);
                float Eg = exp2f(acc[1][j][r]);
                float cc = (Eg - 1.f) * __builtin_amdgcn_rcpf((1.f + ea)*(Eg + 1.f));
                float eo = exp2f(acc[2][j][r]);
                float Ec = exp2f(LOG2E2*cc);
                hv[r] = (Ec - 1.f) * __builtin_amdgcn_rcpf((1.f + eo)*(Ec + 1.f));
            }
            if (dd0 < 90)
                *(unsigned*)(hp + dd0) = pack_bf16(hv[0], hv[1]);
            if (dd0 + 2 < 90)
                *(unsigned*)(hp + dd0 + 2) = pack_bf16(hv[2], hv[3]);
        }
    }
}

// ---------------------------------------------------------------------------
// k2: out GEMM [2048 x 21600] @ [21600 x 48] via MFMA, split-K 45.
// Partials go DIRECTLY into logits via device-scope atomicAdd (removes the
// 17.7MB part2 buffer + its k3a read-back pass). Bias pre-seeded by init.
// ---------------------------------------------------------------------------
__global__ __launch_bounds__(256)
void k2_out(const __bf16* __restrict__ h,
            const __bf16* __restrict__ w2b,
            float* __restrict__ logits)
{
    const int tid  = threadIdx.x;
    const int lane = tid & 63;
    const int wv   = tid >> 6;
    const int l15  = lane & 15;
    const int kg   = lane >> 4;
    const int m0   = (blockIdx.x*4 + wv) * 32;       // 0..2016
    const int chunk= blockIdx.y;                     // 0..44
    const size_t kbase = (size_t)chunk*(KST*32) + 8*kg;

    const __bf16* ha = h   + (size_t)(m0 + l15)*KDIM + kbase;
    const __bf16* hb = ha  + (size_t)16*KDIM;
    const __bf16* w0 = w2b + (size_t)l15*KDIM + kbase;
    const __bf16* w1 = w0  + (size_t)16*KDIM;
    const __bf16* w2 = w0  + (size_t)32*KDIM;

    f32x4 acc00 = {0.f,0.f,0.f,0.f}, acc01 = acc00, acc02 = acc00;
    f32x4 acc10 = acc00, acc11 = acc00, acc12 = acc00;

    #pragma unroll
    for (int s = 0; s < KST; ++s){
        bf16x8 a0 = *(const bf16x8*)(ha + s*32);
        bf16x8 a1 = *(const bf16x8*)(hb + s*32);
        bf16x8 b0 = *(const bf16x8*)(w0 + s*32);
        bf16x8 b1 = *(const bf16x8*)(w1 + s*32);
        bf16x8 b2 = *(const bf16x8*)(w2 + s*32);
        acc00 = __builtin_amdgcn_mfma_f32_16x16x32_bf16(a0, b0, acc00, 0,0,0);
        acc01 = __builtin_amdgcn_mfma_f32_16x16x32_bf16(a0, b1, acc01, 0,0,0);
        acc02 = __builtin_amdgcn_mfma_f32_16x16x32_bf16(a0, b2, acc02, 0,0,0);
        acc10 = __builtin_amdgcn_mfma_f32_16x16x32_bf16(a1, b0, acc10, 0,0,0);
        acc11 = __builtin_amdgcn_mfma_f32_16x16x32_bf16(a1, b1, acc11, 0,0,0);
        acc12 = __builtin_amdgcn_mfma_f32_16x16x32_bf16(a1, b2, acc12, 0,0,0);
    }

    const int rbase = kg*4;
    #pragma unroll
    for (int r = 0; r < 4; ++r){
        size_t row0 = (size_t)(m0 + rbase + r)*NPAD;
        size_t row1 = (size_t)(m0 + 16 + rbase + r)*NPAD;
        atomicAdd(&logits[row0 +      l15], acc00[r]);
        atomicAdd(&logits[row0 + 16 + l15], acc01[r]);
        atomicAdd(&logits[row0 + 32 + l15], acc02[r]);
        atomicAdd(&logits[row1 +      l15], acc10[r]);
        atomicAdd(&logits[row1 + 16 + l15], acc11[r]);
        atomicAdd(&logits[row1 + 32 + l15], acc12[r]);
    }
}

// ---------------------------------------------------------------------------
// k3: softmax over each group of 10. One thread per (b, group).
// ---------------------------------------------------------------------------
__global__ __launch_bounds__(256)
void k3(const float* __restrict__ logits, float* __restrict__ out)
{
    int idx = blockIdx.x*256 + threadIdx.x;   // b*4 + grp
    if (idx >= BB*4) return;
    int b = idx >> 2, grp = idx & 3;
    const float* lg = logits + (size_t)b*NPAD + grp*10;
    float v[10]; float mx = -1e30f;
    #pragma unroll
    for (int q = 0; q < 10; ++q){ v[q] = lg[q]; mx = fmaxf(mx, v[q]); }
    float e[10]; float s = 0.f;
    #pragma unroll
    for (int q = 0; q < 10; ++q){ e[q] = __expf(v[q]-mx); s += e[q]; }
    float inv = 1.0f/s;
    #pragma unroll
    for (int q = 0; q < 10; ++q) out[(size_t)b*NCLS + grp*10 + q] = e[q]*inv;
}

// ---------------------------------------------------------------------------
extern "C" void kernel_launch(void* const* d_in, const int* in_sizes, int n_in,
                              void* d_out, int out_size, void* d_ws, size_t ws_size,
                              hipStream_t stream)
{
    const float* x    = (const float*)d_in[0];
    const float* Wih  = (const float*)d_in[1];
    // d_in[2] = W_hh unused (zero initial hidden state)
    const float* bih  = (const float*)d_in[3];
    const float* bhh  = (const float*)d_in[4];
    const float* W2   = (const float*)d_in[5];
    const float* bout = (const float*)d_in[6];
    float* out = (float*)d_out;

    char* ws = (char*)d_ws;
    size_t off = 0;
    auto alloc = [&](size_t bytes){ void* p = ws + off; off = (off + bytes + 255) & ~(size_t)255; return p; };
    __bf16* h      = (__bf16*)alloc((size_t)MM*DD*2);          // 88.5 MB
    float*  logits = (float*) alloc((size_t)BB*NPAD*4);        // 0.4 MB
    __bf16* wtb    = (__bf16*)alloc(288*104*2);                // 60 KB
    __bf16* w2b    = (__bf16*)alloc((size_t)NPAD*KDIM*2);      // 2.1 MB

    pack1<<<15, 256, 0, stream>>>(Wih, bih, bhh, wtb);
    pack2<<<(NPAD*2700 + 255)/256, 256, 0, stream>>>(W2, w2b);
    init_logits<<<(BB*NPAD + 255)/256, 256, 0, stream>>>(bout, logits);
    k1_gates<<<512, 512, 0, stream>>>(x, wtb, h);
    k2_out<<<dim3(16, KS2), 256, 0, stream>>>(h, w2b, logits);
    k3<<<(BB*4 + 255)/256, 256, 0, stream>>>(logits, out);
}

// Round 17
// 122.065 us; speedup vs baseline: 1.0388x; 1.0388x over previous
//
#include <hip/hip_runtime.h>
#include <hip/hip_bf16.h>

#define BB   2048
#define TT   240
#define DD   90
#define MM   (BB*TT)          // 491520
#define KDIM (TT*DD)          // 21600
#define NCLS 40
#define NPAD 48               // k2 N padded to 3 MFMA col-tiles
#define KS2  27               // k2 split-K chunks (27*25*32 = 21600)
#define KST  25               // k-steps (x32) per chunk

typedef __bf16 bf16x8 __attribute__((ext_vector_type(8)));
typedef float  f32x4  __attribute__((ext_vector_type(4)));

#define LOG2E  1.44269504f
#define LOG2E2 2.88539008f

__device__ __forceinline__ bf16x8 cvt8(float4 a, float4 b){
    bf16x8 r;
    r[0]=(__bf16)a.x; r[1]=(__bf16)a.y; r[2]=(__bf16)a.z; r[3]=(__bf16)a.w;
    r[4]=(__bf16)b.x; r[5]=(__bf16)b.y; r[6]=(__bf16)b.z; r[7]=(__bf16)b.w;
    return r;
}

__device__ __forceinline__ unsigned pack_bf16(float a, float b){
    unsigned u0 = (unsigned)__builtin_bit_cast(unsigned short, (__bf16)a);
    unsigned u1 = (unsigned)__builtin_bit_cast(unsigned short, (__bf16)b);
    return u0 | (u1 << 16);
}

// ---------------------------------------------------------------------------
// pack1 (r14/r15-verified): Wtb[c][k] bf16, c = g*96+dd (gates i,g,o),
// k padded 90->104. Rows PRE-SCALED by exp2 constants (i,o: -log2e;
// g: 2*log2e). k=90: bias-hi, k=91: bias-lo (scaled); x-frag supplies 1.0.
// ---------------------------------------------------------------------------
__global__ void pack1(const float* __restrict__ Wih,
                      const float* __restrict__ bih,
                      const float* __restrict__ bhh,
                      __bf16* __restrict__ wtb)
{
    int id = blockIdx.x*256 + threadIdx.x;
    if (id >= 288*13) return;
    int c  = id / 13;
    int k8 = id - c*13;
    int g  = c / 96, dd = c - g*96;
    int row = (g==0 ? dd : (g==1 ? 180+dd : 270+dd));
    float scale = (g==1) ? LOG2E2 : -LOG2E;
    float bv = 0.f, bhi = 0.f, blo = 0.f;
    if (dd < 90){
        bv  = scale * (bih[row] + bhh[row]);
        bhi = (float)(__bf16)bv;
        blo = bv - bhi;
    }
    bf16x8 v;
    #pragma unroll
    for (int e = 0; e < 8; ++e){
        int k = k8*8 + e;
        float f = 0.f;
        if (dd < 90){
            if (k < 90)       f = scale * Wih[row*90 + k];
            else if (k == 90) f = bhi;
            else if (k == 91) f = blo;
        }
        v[e] = (__bf16)f;
    }
    *(bf16x8*)(wtb + c*104 + k8*8) = v;
}

// ---------------------------------------------------------------------------
// pack2: W_out -> bf16, hi only (r15-verified: absmax unchanged). [48][21600].
// ---------------------------------------------------------------------------
__global__ void pack2(const float* __restrict__ W2, __bf16* __restrict__ w2b)
{
    int id = blockIdx.x*256 + threadIdx.x;
    if (id >= NPAD*2700) return;
    int n  = id / 2700;
    int k8 = id - n*2700;
    bf16x8 v;
    if (n < NCLS){
        #pragma unroll
        for (int e = 0; e < 8; ++e)
            v[e] = (__bf16)W2[(size_t)n*KDIM + k8*8 + e];
    } else {
        #pragma unroll
        for (int e = 0; e < 8; ++e) v[e] = (__bf16)0.f;
    }
    *(bf16x8*)(w2b + (size_t)n*KDIM + k8*8) = v;
}

// ---------------------------------------------------------------------------
// k1: FROZEN (r14/r15-verified 103-us config): W in LDS stride 104,
// launch_bounds(512,2) -> VGPR 96 no spill, single-buffer prefetch,
// C^T MFMA orientation, direct-exp2 epilogue on pre-scaled accumulators.
// ---------------------------------------------------------------------------
__global__ __launch_bounds__(512, 2)
void k1_gates(const float* __restrict__ x,
              const __bf16* __restrict__ wtb,
              __bf16* __restrict__ h)
{
    __shared__ __align__(16) __bf16 wt[288*104];   // 59904 B

    const int tid  = threadIdx.x;
    const int lane = tid & 63;
    const int wv   = tid >> 6;      // 0..7
    const int rg   = wv >> 1;       // row group 0..3
    const int nh   = wv & 1;        // N half 0..1
    const int l15  = lane & 15;
    const int kg   = lane >> 4;     // 0..3

    {
        const float4* src = (const float4*)wtb;
        float4* dst = (float4*)wt;
        #pragma unroll
        for (int i = 0; i < 8; ++i){
            int idx = tid + i*512;
            if (idx < 3744) dst[idx] = src[idx];
        }
    }
    __syncthreads();

    const int tbase = blockIdx.x * 15;     // 512 blocks * 15 tiles * 64 rows

    float4 xr[6];
    float2 xe;
    {
        const float* p = x + ((size_t)tbase*64 + rg*16 + l15)*90;
        #pragma unroll
        for (int ks = 0; ks < 2; ++ks){
            xr[ks*2+0] = *(const float4*)(p + ks*32 + kg*8);
            xr[ks*2+1] = *(const float4*)(p + ks*32 + kg*8 + 4);
        }
        if (kg < 3){
            xr[4] = *(const float4*)(p + 64 + kg*8);
            xr[5] = *(const float4*)(p + 64 + kg*8 + 4);
        } else {
            xe = *(const float2*)(p + 88);
        }
    }

    for (int t = 0; t < 15; ++t){
        bf16x8 af[3];
        af[0] = cvt8(xr[0], xr[1]);
        af[1] = cvt8(xr[2], xr[3]);
        if (kg < 3){
            af[2] = cvt8(xr[4], xr[5]);
        } else {
            bf16x8 z;
            #pragma unroll
            for (int e = 0; e < 8; ++e) z[e] = (__bf16)0.f;
            z[0] = (__bf16)xe.x; z[1] = (__bf16)xe.y;
            z[2] = (__bf16)1.0f; z[3] = (__bf16)1.0f;
            af[2] = z;
        }

        f32x4 acc[3][3];
        #pragma unroll
        for (int g = 0; g < 3; ++g)
            #pragma unroll
            for (int j = 0; j < 3; ++j) acc[g][j] = f32x4{0.f,0.f,0.f,0.f};

        const __bf16* wbase = wt + (nh*48 + l15)*104 + 8*kg;
        #pragma unroll
        for (int g = 0; g < 3; ++g){
            #pragma unroll
            for (int j = 0; j < 3; ++j){
                const __bf16* wrow = wbase + (g*96 + j*16)*104;
                #pragma unroll
                for (int ks = 0; ks < 3; ++ks){
                    bf16x8 wv8 = *(const bf16x8*)(wrow + ks*32);
                    acc[g][j] = __builtin_amdgcn_mfma_f32_16x16x32_bf16(wv8, af[ks], acc[g][j], 0,0,0);
                }
            }
        }

        if (t < 14){
            const float* p = x + ((size_t)(tbase+t+1)*64 + rg*16 + l15)*90;
            #pragma unroll
            for (int ks = 0; ks < 2; ++ks){
                xr[ks*2+0] = *(const float4*)(p + ks*32 + kg*8);
                xr[ks*2+1] = *(const float4*)(p + ks*32 + kg*8 + 4);
            }
            if (kg < 3){
                xr[4] = *(const float4*)(p + 64 + kg*8);
                xr[5] = *(const float4*)(p + 64 + kg*8 + 4);
            } else {
                xe = *(const float2*)(p + 88);
            }
        }

        const size_t mrow = (size_t)(tbase+t)*64 + rg*16 + l15;
        __bf16* hp = h + mrow*90;
        #pragma unroll
        for (int j = 0; j < 3; ++j){
            int dd0 = nh*48 + j*16 + kg*4;
            float hv[4];
            #pragma unroll
            for (int r = 0; r < 4; ++r){
                float ea = exp2f(acc[0][j][r]);
                float Eg = exp2f(acc[1][j][r]);
                float cc = (Eg - 1.f) * __builtin_amdgcn_rcpf((1.f + ea)*(Eg + 1.f));
                float eo = exp2f(acc[2][j][r]);
                float Ec = exp2f(LOG2E2*cc);
                hv[r] = (Ec - 1.f) * __builtin_amdgcn_rcpf((1.f + eo)*(Ec + 1.f));
            }
            if (dd0 < 90)
                *(unsigned*)(hp + dd0) = pack_bf16(hv[0], hv[1]);
            if (dd0 + 2 < 90)
                *(unsigned*)(hp + dd0 + 2) = pack_bf16(hv[2], hv[3]);
        }
    }
}

// ---------------------------------------------------------------------------
// k2: out GEMM [2048 x 21600] @ [21600 x 48] via MFMA, split-K 27
// (was 45: part2 traffic 17.7 -> 10.6 MB; r16's atomic variant contended).
// hi-only W2 (r15-verified).
// ---------------------------------------------------------------------------
__global__ __launch_bounds__(256)
void k2_out(const __bf16* __restrict__ h,
            const __bf16* __restrict__ w2b,
            float* __restrict__ part2)
{
    const int tid  = threadIdx.x;
    const int lane = tid & 63;
    const int wv   = tid >> 6;
    const int l15  = lane & 15;
    const int kg   = lane >> 4;
    const int m0   = (blockIdx.x*4 + wv) * 32;       // 0..2016
    const int chunk= blockIdx.y;                     // 0..26
    const size_t kbase = (size_t)chunk*(KST*32) + 8*kg;

    const __bf16* ha = h   + (size_t)(m0 + l15)*KDIM + kbase;
    const __bf16* hb = ha  + (size_t)16*KDIM;
    const __bf16* w0 = w2b + (size_t)l15*KDIM + kbase;
    const __bf16* w1 = w0  + (size_t)16*KDIM;
    const __bf16* w2 = w0  + (size_t)32*KDIM;

    f32x4 acc00 = {0.f,0.f,0.f,0.f}, acc01 = acc00, acc02 = acc00;
    f32x4 acc10 = acc00, acc11 = acc00, acc12 = acc00;

    #pragma unroll
    for (int s = 0; s < KST; ++s){
        bf16x8 a0 = *(const bf16x8*)(ha + s*32);
        bf16x8 a1 = *(const bf16x8*)(hb + s*32);
        bf16x8 b0 = *(const bf16x8*)(w0 + s*32);
        bf16x8 b1 = *(const bf16x8*)(w1 + s*32);
        bf16x8 b2 = *(const bf16x8*)(w2 + s*32);
        acc00 = __builtin_amdgcn_mfma_f32_16x16x32_bf16(a0, b0, acc00, 0,0,0);
        acc01 = __builtin_amdgcn_mfma_f32_16x16x32_bf16(a0, b1, acc01, 0,0,0);
        acc02 = __builtin_amdgcn_mfma_f32_16x16x32_bf16(a0, b2, acc02, 0,0,0);
        acc10 = __builtin_amdgcn_mfma_f32_16x16x32_bf16(a1, b0, acc10, 0,0,0);
        acc11 = __builtin_amdgcn_mfma_f32_16x16x32_bf16(a1, b1, acc11, 0,0,0);
        acc12 = __builtin_amdgcn_mfma_f32_16x16x32_bf16(a1, b2, acc12, 0,0,0);
    }

    float* pp = part2 + (size_t)chunk*(BB*NPAD);
    const int rbase = kg*4;
    #pragma unroll
    for (int r = 0; r < 4; ++r){
        size_t row0 = (size_t)(m0 + rbase + r)*NPAD;
        size_t row1 = (size_t)(m0 + 16 + rbase + r)*NPAD;
        pp[row0 +      l15] = acc00[r];
        pp[row0 + 16 + l15] = acc01[r];
        pp[row0 + 32 + l15] = acc02[r];
        pp[row1 +      l15] = acc10[r];
        pp[row1 + 16 + l15] = acc11[r];
        pp[row1 + 32 + l15] = acc12[r];
    }
}

// ---------------------------------------------------------------------------
// k3 (fused, r15-verified): reduce split-K partials + bias, then softmax
// over groups of 10. 256 blocks x 384 thr = 8 b-rows x 48 n each.
// ---------------------------------------------------------------------------
__global__ __launch_bounds__(384)
void k3(const float* __restrict__ part2,
        const float* __restrict__ bout,
        float* __restrict__ out)
{
    __shared__ float sm[8*NPAD];
    const int tid  = threadIdx.x;
    const int base = blockIdx.x * 8 * NPAD;      // flat (b*48+n) base

    {
        int g = base + tid;
        float s = 0.f;
        for (int c = 0; c < KS2; ++c) s += part2[(size_t)c*(BB*NPAD) + g];
        int n = tid % NPAD;
        sm[tid] = s + (n < NCLS ? bout[n] : 0.f);
    }
    __syncthreads();

    if (tid < 32){
        int lb  = tid >> 2;      // 0..7
        int grp = tid & 3;       // 0..3
        const float* lg = sm + lb*NPAD + grp*10;
        float v[10]; float mx = -1e30f;
        #pragma unroll
        for (int q = 0; q < 10; ++q){ v[q] = lg[q]; mx = fmaxf(mx, v[q]); }
        float e[10]; float s = 0.f;
        #pragma unroll
        for (int q = 0; q < 10; ++q){ e[q] = __expf(v[q]-mx); s += e[q]; }
        float inv = 1.0f/s;
        size_t b = (size_t)blockIdx.x*8 + lb;
        #pragma unroll
        for (int q = 0; q < 10; ++q) out[b*NCLS + grp*10 + q] = e[q]*inv;
    }
}

// ---------------------------------------------------------------------------
extern "C" void kernel_launch(void* const* d_in, const int* in_sizes, int n_in,
                              void* d_out, int out_size, void* d_ws, size_t ws_size,
                              hipStream_t stream)
{
    const float* x    = (const float*)d_in[0];
    const float* Wih  = (const float*)d_in[1];
    // d_in[2] = W_hh unused (zero initial hidden state)
    const float* bih  = (const float*)d_in[3];
    const float* bhh  = (const float*)d_in[4];
    const float* W2   = (const float*)d_in[5];
    const float* bout = (const float*)d_in[6];
    float* out = (float*)d_out;

    char* ws = (char*)d_ws;
    size_t off = 0;
    auto alloc = [&](size_t bytes){ void* p = ws + off; off = (off + bytes + 255) & ~(size_t)255; return p; };
    __bf16* h     = (__bf16*)alloc((size_t)MM*DD*2);           // 88.5 MB
    float*  part2 = (float*) alloc((size_t)KS2*BB*NPAD*4);     // 10.6 MB
    __bf16* wtb   = (__bf16*)alloc(288*104*2);                 // 60 KB
    __bf16* w2b   = (__bf16*)alloc((size_t)NPAD*KDIM*2);       // 2.1 MB

    pack1<<<15, 256, 0, stream>>>(Wih, bih, bhh, wtb);
    pack2<<<(NPAD*2700 + 255)/256, 256, 0, stream>>>(W2, w2b);
    k1_gates<<<512, 512, 0, stream>>>(x, wtb, h);
    k2_out<<<dim3(16, KS2), 256, 0, stream>>>(h, w2b, part2);
    k3<<<BB/8, 384, 0, stream>>>(part2, bout, out);
}